// Round 3
// baseline (500.900 us; speedup 1.0000x reference)
//
#include <hip/hip_runtime.h>

static inline int idiv_up(long a, long b) { return (int)((a + b - 1) / b); }

// ---------------------------------------------------------------------------
// Kernel 0: fold weights.  Wcomb[f][j] = sum_c W_emb[f][c]*Wcat[c][j]
// column map j: [0,128)=Q (h=j>>5,k=j&31), [128,256)=K, [256,320)=V0
// ---------------------------------------------------------------------------
__global__ __launch_bounds__(256) void fold_weights(
    const float* __restrict__ W_emb, const float* __restrict__ b_emb,
    const float* __restrict__ Wq, const float* __restrict__ Wk,
    const float* __restrict__ Wv0,
    float* __restrict__ Wcomb, float* __restrict__ bcomb)
{
    int idx = blockIdx.x * 256 + threadIdx.x;
    if (idx >= 33 * 320) return;
    int row = idx / 320, j = idx - row * 320;
    float acc = 0.f;
    for (int c = 0; c < 64; ++c) {
        float w;
        if (j < 128)      { int h = j >> 5,         k = j & 31;         w = Wq [(h * 64 + c) * 32 + k]; }
        else if (j < 256) { int h = (j - 128) >> 5, k = (j - 128) & 31; w = Wk [(h * 64 + c) * 32 + k]; }
        else              { int h = (j - 256) >> 4, v = (j - 256) & 15; w = Wv0[(h * 64 + c) * 16 + v]; }
        float lhs = (row < 32) ? W_emb[row * 64 + c] : b_emb[c];
        acc += lhs * w;
    }
    if (row < 32) Wcomb[row * 320 + j] = acc;
    else          bcomb[j] = acc;
}

// ---------------------------------------------------------------------------
// Kernel 1: per-node QKV tables. QKV[n][0:128]=Q [128:256]=K [256:320]=V0
// ---------------------------------------------------------------------------
__global__ __launch_bounds__(256) void node_qkv(
    const float* __restrict__ nf, const float* __restrict__ Wcomb,
    const float* __restrict__ bcomb, float* __restrict__ QKV, int Nn)
{
    int c    = blockIdx.x % 10;
    int tile = blockIdx.x / 10;
    __shared__ float sW[32][32];
    __shared__ float sb[32];
    for (int i = threadIdx.x; i < 1024; i += 256) {
        int f = i >> 5, j = i & 31;
        sW[f][j] = Wcomb[f * 320 + c * 32 + j];
    }
    if (threadIdx.x < 32) sb[threadIdx.x] = bcomb[c * 32 + threadIdx.x];
    __syncthreads();
    int n = tile * 256 + threadIdx.x;
    if (n >= Nn) return;

    float nfv[32];
    const float4* nfp = (const float4*)(nf + (size_t)n * 32);
#pragma unroll
    for (int f4 = 0; f4 < 8; ++f4) {
        float4 v = nfp[f4];
        nfv[f4 * 4 + 0] = v.x; nfv[f4 * 4 + 1] = v.y;
        nfv[f4 * 4 + 2] = v.z; nfv[f4 * 4 + 3] = v.w;
    }
    float acc[32];
#pragma unroll
    for (int j = 0; j < 32; ++j) acc[j] = sb[j];
#pragma unroll
    for (int f = 0; f < 32; ++f) {
        float x = nfv[f];
#pragma unroll
        for (int j4 = 0; j4 < 8; ++j4) {
            float4 w = *(const float4*)&sW[f][j4 * 4];
            acc[j4 * 4 + 0] += x * w.x; acc[j4 * 4 + 1] += x * w.y;
            acc[j4 * 4 + 2] += x * w.z; acc[j4 * 4 + 3] += x * w.w;
        }
    }
    float4* outp = (float4*)(QKV + (size_t)n * 320 + c * 32);
#pragma unroll
    for (int j4 = 0; j4 < 8; ++j4) {
        float4 v;
        v.x = acc[j4 * 4 + 0]; v.y = acc[j4 * 4 + 1];
        v.z = acc[j4 * 4 + 2]; v.w = acc[j4 * 4 + 3];
        outp[j4] = v;
    }
}

// ---------------------------------------------------------------------------
// Kernel 2: degree count
// ---------------------------------------------------------------------------
__global__ __launch_bounds__(256) void count_deg(
    const int* __restrict__ ei, int* __restrict__ deg, int Ee)
{
    int e = blockIdx.x * 256 + threadIdx.x;
    if (e >= Ee) return;
    atomicAdd(&deg[ei[Ee + e]], 1);
}

// ---------------------------------------------------------------------------
// Kernel 3: exclusive scan of deg -> offs, cursor (single block, 1024 thr)
// ---------------------------------------------------------------------------
__global__ __launch_bounds__(1024) void scan_deg(
    const int* __restrict__ deg, int* __restrict__ offs,
    int* __restrict__ cursor, int Nn)
{
    __shared__ int part[1024];
    int chunk = (Nn + 1023) / 1024;
    int start = threadIdx.x * chunk;
    int end   = min(start + chunk, Nn);
    int s = 0;
    for (int i = start; i < end; ++i) s += deg[i];
    part[threadIdx.x] = s;
    __syncthreads();
    for (int off = 1; off < 1024; off <<= 1) {
        int v = 0;
        if ((int)threadIdx.x >= off) v = part[threadIdx.x - off];
        __syncthreads();
        if ((int)threadIdx.x >= off) part[threadIdx.x] += v;
        __syncthreads();
    }
    int excl = (threadIdx.x == 0) ? 0 : part[threadIdx.x - 1];
    for (int i = start; i < end; ++i) {
        offs[i] = excl; cursor[i] = excl;
        excl += deg[i];
    }
}

// ---------------------------------------------------------------------------
// Kernel 4: scatter edges into CSR-by-dst; pack (src, d) as int2, one 8B store.
// ---------------------------------------------------------------------------
__global__ __launch_bounds__(256) void scatter_edges(
    const float* __restrict__ pos, const int* __restrict__ ei,
    int* __restrict__ cursor, int2* __restrict__ csr, int Ee)
{
    int e = blockIdx.x * 256 + threadIdx.x;
    if (e >= Ee) return;
    int s  = ei[e];
    int dg = ei[Ee + e];
    float dx = pos[(size_t)dg * 3 + 0] - pos[(size_t)s * 3 + 0];
    float dy = pos[(size_t)dg * 3 + 1] - pos[(size_t)s * 3 + 1];
    float dz = pos[(size_t)dg * 3 + 2] - pos[(size_t)s * 3 + 2];
    float d = sqrtf(dx * dx + dy * dy + dz * dz) + 1e-8f;
    int p = atomicAdd(&cursor[dg], 1);
    int2 pk; pk.x = s; pk.y = __float_as_int(d);
    csr[p] = pk;
}

// ---------------------------------------------------------------------------
// Kernel 5: fused per-node attention. ONE WAVE PER NODE (grid covers all N).
// Lane layout: h = lane>>4, j = lane&15. 2-edge unrolled online softmax.
// ---------------------------------------------------------------------------
__global__ __launch_bounds__(256) void node_attn(
    const float* __restrict__ QKV, const int2* __restrict__ csr,
    const int* __restrict__ offs, const int* __restrict__ deg,
    const int* __restrict__ batch,
    const float* __restrict__ R1, const float* __restrict__ b1,
    const float* __restrict__ R2, const float* __restrict__ b2,
    float* __restrict__ pooled, int Nn)
{
    int lane = threadIdx.x & 63;
    int h = lane >> 4, j = lane & 15;
    int hb = h << 4;
    int waveId = blockIdx.x * (blockDim.x >> 6) + (threadIdx.x >> 6);
    int nWaves = gridDim.x * (blockDim.x >> 6);

    // R2 live columns in registers: c0=col j, c1=col j+16 (rk), c2=col 32+j (rv0)
    float c0[16], c1[16], c2[16];
#pragma unroll
    for (int r = 0; r < 16; ++r) {
        const float* row = R2 + (size_t)(h * 16 + r) * 64;
        c0[r] = row[j]; c1[r] = row[j + 16]; c2[r] = row[32 + j];
    }
    float r1l = R1[lane], b1l = b1[lane];
    float bk0 = b2[h * 64 + j];
    float bk1 = b2[h * 64 + j + 16];
    float bv  = b2[h * 64 + 32 + j];
    const float rs = 0.17677669529663687f; // 1/sqrt(32)

    for (int n = waveId; n < Nn; n += nWaves) {
        int start = offs[n], cnt = deg[n];
        if (cnt == 0) continue;
        float q0 = QKV[(size_t)n * 320 + hb * 2 + j];
        float q1 = QKV[(size_t)n * 320 + hb * 2 + j + 16];
        float m = -3.0e38f, l = 0.f, acc = 0.f;
        int e = start, end = start + cnt;
        for (; e + 1 < end; e += 2) {
            int2 pk0 = csr[e], pk1 = csr[e + 1];
            int   s0 = pk0.x, s1 = pk1.x;
            float d0 = __int_as_float(pk0.y), d1 = __int_as_float(pk1.y);
            const float* B0 = QKV + (size_t)s0 * 320;
            const float* B1 = QKV + (size_t)s1 * 320;
            float k00 = B0[128 + hb * 2 + j];
            float k01 = B0[128 + hb * 2 + j + 16];
            float v00 = B0[256 + lane];
            float k10 = B1[128 + hb * 2 + j];
            float k11 = B1[128 + hb * 2 + j + 16];
            float v10 = B1[256 + lane];
            float x0  = fmaf(d0, r1l, b1l);
            float x1  = fmaf(d1, r1l, b1l);
            float rh0 = x0 / (1.f + __expf(-x0));
            float rh1 = x1 / (1.f + __expf(-x1));
            float rk00 = bk0, rk01 = bk1, rv0 = bv;
            float rk10 = bk0, rk11 = bk1, rv1 = bv;
#pragma unroll
            for (int r = 0; r < 16; ++r) {
                float rr0 = __shfl(rh0, hb + r);
                float rr1 = __shfl(rh1, hb + r);
                rk00 = fmaf(rr0, c0[r], rk00);
                rk10 = fmaf(rr1, c0[r], rk10);
                rk01 = fmaf(rr0, c1[r], rk01);
                rk11 = fmaf(rr1, c1[r], rk11);
                rv0  = fmaf(rr0, c2[r], rv0);
                rv1  = fmaf(rr1, c2[r], rv1);
            }
            float p0 = q0 * k00 * rk00 + q1 * k01 * rk01;
            float p1 = q0 * k10 * rk10 + q1 * k11 * rk11;
            p0 += __shfl_xor(p0, 1);  p1 += __shfl_xor(p1, 1);
            p0 += __shfl_xor(p0, 2);  p1 += __shfl_xor(p1, 2);
            p0 += __shfl_xor(p0, 4);  p1 += __shfl_xor(p1, 4);
            p0 += __shfl_xor(p0, 8);  p1 += __shfl_xor(p1, 8);
            float sc0 = p0 * rs, sc1 = p1 * rs;
            float mn  = fmaxf(m, fmaxf(sc0, sc1));          // v_max3
            float sca = __expf(m - mn);
            float ex0 = __expf(sc0 - mn);
            float ex1 = __expf(sc1 - mn);
            l   = fmaf(l, sca, ex0 + ex1);
            acc = fmaf(acc, sca, fmaf(ex0, v00 * rv0, ex1 * (v10 * rv1)));
            m = mn;
        }
        if (e < end) {
            int2 pk0 = csr[e];
            int   s0 = pk0.x;
            float d0 = __int_as_float(pk0.y);
            const float* B0 = QKV + (size_t)s0 * 320;
            float k00 = B0[128 + hb * 2 + j];
            float k01 = B0[128 + hb * 2 + j + 16];
            float v00 = B0[256 + lane];
            float x0  = fmaf(d0, r1l, b1l);
            float rh0 = x0 / (1.f + __expf(-x0));
            float rk00 = bk0, rk01 = bk1, rv0 = bv;
#pragma unroll
            for (int r = 0; r < 16; ++r) {
                float rr0 = __shfl(rh0, hb + r);
                rk00 = fmaf(rr0, c0[r], rk00);
                rk01 = fmaf(rr0, c1[r], rk01);
                rv0  = fmaf(rr0, c2[r], rv0);
            }
            float p0 = q0 * k00 * rk00 + q1 * k01 * rk01;
            p0 += __shfl_xor(p0, 1);
            p0 += __shfl_xor(p0, 2);
            p0 += __shfl_xor(p0, 4);
            p0 += __shfl_xor(p0, 8);
            float sc0 = p0 * rs;
            float mn  = fmaxf(m, sc0);
            float sca = __expf(m - mn);
            float ex0 = __expf(sc0 - mn);
            l   = fmaf(l, sca, ex0);
            acc = fmaf(acc, sca, ex0 * (v00 * rv0));
            m = mn;
        }
        float o = acc / (l + 1e-9f);
        atomicAdd(&pooled[(size_t)batch[n] * 64 + lane], o);
    }
}

// ---------------------------------------------------------------------------
// Kernel 6: out[b][o] = sum_i pooled[b][i] * Wproj[i][o]
// ---------------------------------------------------------------------------
__global__ __launch_bounds__(256) void final_proj(
    const float* __restrict__ pooled, const float* __restrict__ Wproj,
    float* __restrict__ out, int total)
{
    int idx = blockIdx.x * 256 + threadIdx.x;
    if (idx >= total) return;
    int b = idx >> 6, o = idx & 63;
    float acc = 0.f;
#pragma unroll
    for (int i = 0; i < 64; ++i) acc += pooled[b * 64 + i] * Wproj[i * 64 + o];
    out[idx] = acc;
}

extern "C" void kernel_launch(void* const* d_in, const int* in_sizes, int n_in,
                              void* d_out, int out_size, void* d_ws, size_t ws_size,
                              hipStream_t stream)
{
    const float* pos   = (const float*)d_in[0];
    const float* nf    = (const float*)d_in[1];
    const int*   ei    = (const int*)d_in[2];
    const int*   batch = (const int*)d_in[3];
    const float* W_emb = (const float*)d_in[4];
    const float* b_emb = (const float*)d_in[5];
    const float* Wq    = (const float*)d_in[6];
    const float* Wk    = (const float*)d_in[7];
    const float* Wv0   = (const float*)d_in[8];
    const float* R1    = (const float*)d_in[10];
    const float* b1    = (const float*)d_in[11];
    const float* R2    = (const float*)d_in[12];
    const float* b2    = (const float*)d_in[13];
    const float* Wproj = (const float*)d_in[14];
    float* out = (float*)d_out;

    long Nn = in_sizes[0] / 3;
    long Ee = in_sizes[2] / 2;
    int  Bb = out_size / 64;

    float* ws = (float*)d_ws;
    size_t WCOMB = 0;
    size_t BCOMB = WCOMB + 32 * 320;
    size_t QKV_O = BCOMB + 320;
    size_t DEG   = QKV_O + (size_t)Nn * 320;
    size_t POOL  = DEG + (size_t)Nn;            // contiguous with DEG for one memset
    size_t OFFS  = POOL + (size_t)Bb * 64;
    size_t CURS  = OFFS + (size_t)Nn;
    size_t CSR   = CURS + (size_t)Nn;           // int2 per edge (even float offset)

    hipMemsetAsync(ws + DEG, 0, ((size_t)Nn + (size_t)Bb * 64) * sizeof(float), stream);

    fold_weights<<<idiv_up(33 * 320, 256), 256, 0, stream>>>(
        W_emb, b_emb, Wq, Wk, Wv0, ws + WCOMB, ws + BCOMB);

    node_qkv<<<idiv_up(Nn, 256) * 10, 256, 0, stream>>>(
        nf, ws + WCOMB, ws + BCOMB, ws + QKV_O, (int)Nn);

    count_deg<<<idiv_up(Ee, 256), 256, 0, stream>>>(
        ei, (int*)(ws + DEG), (int)Ee);

    scan_deg<<<1, 1024, 0, stream>>>(
        (const int*)(ws + DEG), (int*)(ws + OFFS), (int*)(ws + CURS), (int)Nn);

    scatter_edges<<<idiv_up(Ee, 256), 256, 0, stream>>>(
        pos, ei, (int*)(ws + CURS), (int2*)(ws + CSR), (int)Ee);

    // one wave per node: 4 waves per 256-thread block
    node_attn<<<idiv_up(Nn, 4), 256, 0, stream>>>(
        ws + QKV_O, (const int2*)(ws + CSR),
        (const int*)(ws + OFFS), (const int*)(ws + DEG), batch,
        R1, b1, R2, b2, ws + POOL, (int)Nn);

    final_proj<<<idiv_up(out_size, 256), 256, 0, stream>>>(
        ws + POOL, Wproj, out, out_size);
}

// Round 4
// 444.069 us; speedup vs baseline: 1.1280x; 1.1280x over previous
//
#include <hip/hip_runtime.h>

static inline int idiv_up(long a, long b) { return (int)((a + b - 1) / b); }

__device__ __forceinline__ unsigned short f2bf(float f) {
    unsigned b = __float_as_uint(f);
    return (unsigned short)((b + 0x7FFFu + ((b >> 16) & 1u)) >> 16);
}

// ---------------------------------------------------------------------------
// Kernel 0: fold weights.  Wcomb[f][j] = sum_c W_emb[f][c]*Wcat[c][j]
// column map j: [0,128)=Q (h=j>>5,k=j&31), [128,256)=K, [256,320)=V0
// ---------------------------------------------------------------------------
__global__ __launch_bounds__(256) void fold_weights(
    const float* __restrict__ W_emb, const float* __restrict__ b_emb,
    const float* __restrict__ Wq, const float* __restrict__ Wk,
    const float* __restrict__ Wv0,
    float* __restrict__ Wcomb, float* __restrict__ bcomb)
{
    int idx = blockIdx.x * 256 + threadIdx.x;
    if (idx >= 33 * 320) return;
    int row = idx / 320, j = idx - row * 320;
    float acc = 0.f;
    for (int c = 0; c < 64; ++c) {
        float w;
        if (j < 128)      { int h = j >> 5,         k = j & 31;         w = Wq [(h * 64 + c) * 32 + k]; }
        else if (j < 256) { int h = (j - 128) >> 5, k = (j - 128) & 31; w = Wk [(h * 64 + c) * 32 + k]; }
        else              { int h = (j - 256) >> 4, v = (j - 256) & 15; w = Wv0[(h * 64 + c) * 16 + v]; }
        float lhs = (row < 32) ? W_emb[row * 64 + c] : b_emb[c];
        acc += lhs * w;
    }
    if (row < 32) Wcomb[row * 320 + j] = acc;
    else          bcomb[j] = acc;
}

// ---------------------------------------------------------------------------
// Kernel 1: per-node tables.
//   Qtab [n][128] f32  (col h*32+j / +16)  -- streamed per dst, coalesced
//   Ktab [n][64] uint  (lane h*16+j: low16=bf16(k0 @ h*32+j), high16=bf16(k1))
//   Vtab [n][64] u16   (lane h*16+j: bf16(v @ h*16+j))
// ---------------------------------------------------------------------------
__global__ __launch_bounds__(256) void node_qkv(
    const float* __restrict__ nf, const float* __restrict__ Wcomb,
    const float* __restrict__ bcomb, float* __restrict__ Qtab,
    unsigned* __restrict__ Ktab, unsigned short* __restrict__ Vtab, int Nn)
{
    int c    = blockIdx.x % 10;
    int tile = blockIdx.x / 10;
    __shared__ float sW[32][32];
    __shared__ float sb[32];
    for (int i = threadIdx.x; i < 1024; i += 256) {
        int f = i >> 5, j = i & 31;
        sW[f][j] = Wcomb[f * 320 + c * 32 + j];
    }
    if (threadIdx.x < 32) sb[threadIdx.x] = bcomb[c * 32 + threadIdx.x];
    __syncthreads();
    int n = tile * 256 + threadIdx.x;
    if (n >= Nn) return;

    float nfv[32];
    const float4* nfp = (const float4*)(nf + (size_t)n * 32);
#pragma unroll
    for (int f4 = 0; f4 < 8; ++f4) {
        float4 v = nfp[f4];
        nfv[f4 * 4 + 0] = v.x; nfv[f4 * 4 + 1] = v.y;
        nfv[f4 * 4 + 2] = v.z; nfv[f4 * 4 + 3] = v.w;
    }
    float acc[32];
#pragma unroll
    for (int j = 0; j < 32; ++j) acc[j] = sb[j];
#pragma unroll
    for (int f = 0; f < 32; ++f) {
        float x = nfv[f];
#pragma unroll
        for (int j4 = 0; j4 < 8; ++j4) {
            float4 w = *(const float4*)&sW[f][j4 * 4];
            acc[j4 * 4 + 0] += x * w.x; acc[j4 * 4 + 1] += x * w.y;
            acc[j4 * 4 + 2] += x * w.z; acc[j4 * 4 + 3] += x * w.w;
        }
    }
    if (c < 4) {
        float4* outp = (float4*)(Qtab + (size_t)n * 128 + c * 32);
#pragma unroll
        for (int j4 = 0; j4 < 8; ++j4) {
            float4 v;
            v.x = acc[j4 * 4 + 0]; v.y = acc[j4 * 4 + 1];
            v.z = acc[j4 * 4 + 2]; v.w = acc[j4 * 4 + 3];
            outp[j4] = v;
        }
    } else if (c < 8) {
        int h = c - 4;
        unsigned* kp = Ktab + (size_t)n * 64 + h * 16;
#pragma unroll
        for (int j = 0; j < 16; ++j)
            kp[j] = (unsigned)f2bf(acc[j]) | ((unsigned)f2bf(acc[j + 16]) << 16);
    } else {
        unsigned short* vp = Vtab + (size_t)n * 64 + (c - 8) * 32;
#pragma unroll
        for (int j = 0; j < 32; ++j) vp[j] = f2bf(acc[j]);
    }
}

// ---------------------------------------------------------------------------
// Kernel 2: degree count
// ---------------------------------------------------------------------------
__global__ __launch_bounds__(256) void count_deg(
    const int* __restrict__ ei, int* __restrict__ deg, int Ee)
{
    int e = blockIdx.x * 256 + threadIdx.x;
    if (e >= Ee) return;
    atomicAdd(&deg[ei[Ee + e]], 1);
}

// ---------------------------------------------------------------------------
// Kernel 3: offsets via wave prefix-sum + one atomic per wave.
// CSR segment ORDER is irrelevant (only contiguity matters), so unordered
// base allocation is fine.
// ---------------------------------------------------------------------------
__global__ __launch_bounds__(256) void calc_offs(
    const int* __restrict__ deg, int* __restrict__ offs,
    int* __restrict__ cursor, int* __restrict__ gtot, int Nn)
{
    int n = blockIdx.x * 256 + threadIdx.x;
    int lane = threadIdx.x & 63;
    int d = (n < Nn) ? deg[n] : 0;
    int pre = d;
#pragma unroll
    for (int s = 1; s < 64; s <<= 1) {
        int t = __shfl_up(pre, s);
        if (lane >= s) pre += t;
    }
    int waveTot = __shfl(pre, 63);
    int base = 0;
    if (lane == 63) base = atomicAdd(gtot, waveTot);
    base = __shfl(base, 63);
    if (n < Nn) {
        int off = base + pre - d;
        offs[n] = off; cursor[n] = off;
    }
}

// ---------------------------------------------------------------------------
// Kernel 4: scatter edges into CSR-by-dst; pack (src, d) as int2.
// ---------------------------------------------------------------------------
__global__ __launch_bounds__(256) void scatter_edges(
    const float* __restrict__ pos, const int* __restrict__ ei,
    int* __restrict__ cursor, int2* __restrict__ csr, int Ee)
{
    int e = blockIdx.x * 256 + threadIdx.x;
    if (e >= Ee) return;
    int s  = ei[e];
    int dg = ei[Ee + e];
    float dx = pos[(size_t)dg * 3 + 0] - pos[(size_t)s * 3 + 0];
    float dy = pos[(size_t)dg * 3 + 1] - pos[(size_t)s * 3 + 1];
    float dz = pos[(size_t)dg * 3 + 2] - pos[(size_t)s * 3 + 2];
    float d = sqrtf(dx * dx + dy * dy + dz * dz) + 1e-8f;
    int p = atomicAdd(&cursor[dg], 1);
    int2 pk; pk.x = s; pk.y = __float_as_int(d);
    csr[p] = pk;
}

// ---------------------------------------------------------------------------
// Kernel 5: fused per-node attention, wave per node via grid-stride
// (~3 nodes/wave amortizes the R2 preamble). Lane layout: h=lane>>4, j=lane&15.
// Gather = 4B Ktab + 2B Vtab per lane per edge (bf16-packed).
// ---------------------------------------------------------------------------
__global__ __launch_bounds__(256) void node_attn(
    const float* __restrict__ Qtab, const unsigned* __restrict__ Ktab,
    const unsigned short* __restrict__ Vtab, const int2* __restrict__ csr,
    const int* __restrict__ offs, const int* __restrict__ deg,
    const int* __restrict__ batch,
    const float* __restrict__ R1, const float* __restrict__ b1,
    const float* __restrict__ R2, const float* __restrict__ b2,
    float* __restrict__ pooled, int Nn)
{
    int lane = threadIdx.x & 63;
    int h = lane >> 4, j = lane & 15;
    int hb = h << 4;
    int waveId = blockIdx.x * (blockDim.x >> 6) + (threadIdx.x >> 6);
    int nWaves = gridDim.x * (blockDim.x >> 6);

    float c0[16], c1[16], c2[16];
#pragma unroll
    for (int r = 0; r < 16; ++r) {
        const float* row = R2 + (size_t)(h * 16 + r) * 64;
        c0[r] = row[j]; c1[r] = row[j + 16]; c2[r] = row[32 + j];
    }
    float r1l = R1[lane], b1l = b1[lane];
    float bk0 = b2[h * 64 + j];
    float bk1 = b2[h * 64 + j + 16];
    float bv  = b2[h * 64 + 32 + j];
    const float rs = 0.17677669529663687f; // 1/sqrt(32)

    for (int n = waveId; n < Nn; n += nWaves) {
        int start = offs[n], cnt = deg[n];
        if (cnt == 0) continue;
        float q0 = Qtab[(size_t)n * 128 + h * 32 + j];
        float q1 = Qtab[(size_t)n * 128 + h * 32 + j + 16];
        float m = -3.0e38f, l = 0.f, acc = 0.f;
        int e = start, end = start + cnt;
        for (; e + 1 < end; e += 2) {
            int2 pk0 = csr[e], pk1 = csr[e + 1];
            int   s0 = pk0.x, s1 = pk1.x;
            float d0 = __int_as_float(pk0.y), d1 = __int_as_float(pk1.y);
            unsigned       ku0 = Ktab[(size_t)s0 * 64 + lane];
            unsigned       ku1 = Ktab[(size_t)s1 * 64 + lane];
            unsigned short vu0 = Vtab[(size_t)s0 * 64 + lane];
            unsigned short vu1 = Vtab[(size_t)s1 * 64 + lane];
            float k00 = __uint_as_float(ku0 << 16);
            float k01 = __uint_as_float(ku0 & 0xFFFF0000u);
            float k10 = __uint_as_float(ku1 << 16);
            float k11 = __uint_as_float(ku1 & 0xFFFF0000u);
            float v00 = __uint_as_float((unsigned)vu0 << 16);
            float v10 = __uint_as_float((unsigned)vu1 << 16);
            float x0  = fmaf(d0, r1l, b1l);
            float x1  = fmaf(d1, r1l, b1l);
            float rh0 = x0 / (1.f + __expf(-x0));
            float rh1 = x1 / (1.f + __expf(-x1));
            float rk00 = bk0, rk01 = bk1, rv0 = bv;
            float rk10 = bk0, rk11 = bk1, rv1 = bv;
#pragma unroll
            for (int r = 0; r < 16; ++r) {
                float rr0 = __shfl(rh0, hb + r);
                float rr1 = __shfl(rh1, hb + r);
                rk00 = fmaf(rr0, c0[r], rk00);
                rk10 = fmaf(rr1, c0[r], rk10);
                rk01 = fmaf(rr0, c1[r], rk01);
                rk11 = fmaf(rr1, c1[r], rk11);
                rv0  = fmaf(rr0, c2[r], rv0);
                rv1  = fmaf(rr1, c2[r], rv1);
            }
            float p0 = q0 * k00 * rk00 + q1 * k01 * rk01;
            float p1 = q0 * k10 * rk10 + q1 * k11 * rk11;
            p0 += __shfl_xor(p0, 1);  p1 += __shfl_xor(p1, 1);
            p0 += __shfl_xor(p0, 2);  p1 += __shfl_xor(p1, 2);
            p0 += __shfl_xor(p0, 4);  p1 += __shfl_xor(p1, 4);
            p0 += __shfl_xor(p0, 8);  p1 += __shfl_xor(p1, 8);
            float sc0 = p0 * rs, sc1 = p1 * rs;
            float mn  = fmaxf(m, fmaxf(sc0, sc1));
            float sca = __expf(m - mn);
            float ex0 = __expf(sc0 - mn);
            float ex1 = __expf(sc1 - mn);
            l   = fmaf(l, sca, ex0 + ex1);
            acc = fmaf(acc, sca, fmaf(ex0, v00 * rv0, ex1 * (v10 * rv1)));
            m = mn;
        }
        if (e < end) {
            int2 pk0 = csr[e];
            int   s0 = pk0.x;
            float d0 = __int_as_float(pk0.y);
            unsigned       ku0 = Ktab[(size_t)s0 * 64 + lane];
            unsigned short vu0 = Vtab[(size_t)s0 * 64 + lane];
            float k00 = __uint_as_float(ku0 << 16);
            float k01 = __uint_as_float(ku0 & 0xFFFF0000u);
            float v00 = __uint_as_float((unsigned)vu0 << 16);
            float x0  = fmaf(d0, r1l, b1l);
            float rh0 = x0 / (1.f + __expf(-x0));
            float rk00 = bk0, rk01 = bk1, rv0 = bv;
#pragma unroll
            for (int r = 0; r < 16; ++r) {
                float rr0 = __shfl(rh0, hb + r);
                rk00 = fmaf(rr0, c0[r], rk00);
                rk01 = fmaf(rr0, c1[r], rk01);
                rv0  = fmaf(rr0, c2[r], rv0);
            }
            float p0 = q0 * k00 * rk00 + q1 * k01 * rk01;
            p0 += __shfl_xor(p0, 1);
            p0 += __shfl_xor(p0, 2);
            p0 += __shfl_xor(p0, 4);
            p0 += __shfl_xor(p0, 8);
            float sc0 = p0 * rs;
            float mn  = fmaxf(m, sc0);
            float sca = __expf(m - mn);
            float ex0 = __expf(sc0 - mn);
            l   = fmaf(l, sca, ex0);
            acc = fmaf(acc, sca, ex0 * (v00 * rv0));
            m = mn;
        }
        float o = acc / (l + 1e-9f);
        atomicAdd(&pooled[(size_t)batch[n] * 64 + lane], o);
    }
}

// ---------------------------------------------------------------------------
// Kernel 6: out[b][o] = sum_i pooled[b][i] * Wproj[i][o]
// ---------------------------------------------------------------------------
__global__ __launch_bounds__(256) void final_proj(
    const float* __restrict__ pooled, const float* __restrict__ Wproj,
    float* __restrict__ out, int total)
{
    int idx = blockIdx.x * 256 + threadIdx.x;
    if (idx >= total) return;
    int b = idx >> 6, o = idx & 63;
    float acc = 0.f;
#pragma unroll
    for (int i = 0; i < 64; ++i) acc += pooled[b * 64 + i] * Wproj[i * 64 + o];
    out[idx] = acc;
}

extern "C" void kernel_launch(void* const* d_in, const int* in_sizes, int n_in,
                              void* d_out, int out_size, void* d_ws, size_t ws_size,
                              hipStream_t stream)
{
    const float* pos   = (const float*)d_in[0];
    const float* nf    = (const float*)d_in[1];
    const int*   ei    = (const int*)d_in[2];
    const int*   batch = (const int*)d_in[3];
    const float* W_emb = (const float*)d_in[4];
    const float* b_emb = (const float*)d_in[5];
    const float* Wq    = (const float*)d_in[6];
    const float* Wk    = (const float*)d_in[7];
    const float* Wv0   = (const float*)d_in[8];
    const float* R1    = (const float*)d_in[10];
    const float* b1    = (const float*)d_in[11];
    const float* R2    = (const float*)d_in[12];
    const float* b2    = (const float*)d_in[13];
    const float* Wproj = (const float*)d_in[14];
    float* out = (float*)d_out;

    long Nn = in_sizes[0] / 3;
    long Ee = in_sizes[2] / 2;
    int  Bb = out_size / 64;

    float* ws = (float*)d_ws;
    size_t WCOMB = 0;
    size_t BCOMB = WCOMB + 32 * 320;
    size_t QTAB  = BCOMB + 320;                  // N*128 f32
    size_t KTAB  = QTAB + (size_t)Nn * 128;      // N*64 uint
    size_t VTAB  = KTAB + (size_t)Nn * 64;       // N*64 u16 = N*32 f32 slots
    size_t DEG   = VTAB + (size_t)Nn * 32;       // N int (zeroed)
    size_t GTOT  = DEG + (size_t)Nn;             // 2 slots (zeroed, keeps evenness)
    size_t POOL  = GTOT + 2;                     // B*64 f32 (zeroed)
    size_t OFFS  = POOL + (size_t)Bb * 64;
    size_t CURS  = OFFS + (size_t)Nn;
    size_t CSR   = CURS + (size_t)Nn;            // int2 per edge (8B aligned: even)

    hipMemsetAsync(ws + DEG, 0, ((size_t)Nn + 2 + (size_t)Bb * 64) * sizeof(float), stream);

    fold_weights<<<idiv_up(33 * 320, 256), 256, 0, stream>>>(
        W_emb, b_emb, Wq, Wk, Wv0, ws + WCOMB, ws + BCOMB);

    node_qkv<<<idiv_up(Nn, 256) * 10, 256, 0, stream>>>(
        nf, ws + WCOMB, ws + BCOMB, ws + QTAB,
        (unsigned*)(ws + KTAB), (unsigned short*)(ws + VTAB), (int)Nn);

    count_deg<<<idiv_up(Ee, 256), 256, 0, stream>>>(
        ei, (int*)(ws + DEG), (int)Ee);

    calc_offs<<<idiv_up(Nn, 256), 256, 0, stream>>>(
        (const int*)(ws + DEG), (int*)(ws + OFFS), (int*)(ws + CURS),
        (int*)(ws + GTOT), (int)Nn);

    scatter_edges<<<idiv_up(Ee, 256), 256, 0, stream>>>(
        pos, ei, (int*)(ws + CURS), (int2*)(ws + CSR), (int)Ee);

    node_attn<<<4096, 256, 0, stream>>>(
        ws + QTAB, (const unsigned*)(ws + KTAB), (const unsigned short*)(ws + VTAB),
        (const int2*)(ws + CSR), (const int*)(ws + OFFS), (const int*)(ws + DEG),
        batch, R1, b1, R2, b2, ws + POOL, (int)Nn);

    final_proj<<<idiv_up(out_size, 256), 256, 0, stream>>>(
        ws + POOL, Wproj, out, out_size);
}

// Round 5
// 420.115 us; speedup vs baseline: 1.1923x; 1.0570x over previous
//
#include <hip/hip_runtime.h>
#include <hip/hip_fp16.h>

static inline int idiv_up(long a, long b) { return (int)((a + b - 1) / b); }

typedef float v2f __attribute__((ext_vector_type(2)));

__device__ __forceinline__ unsigned pack_h2(float a, float b) {
    __half2 t = __floats2half2_rn(a, b);
    return *reinterpret_cast<unsigned*>(&t);
}
__device__ __forceinline__ unsigned short pack_h1(float a) {
    __half t = __float2half_rn(a);
    return *reinterpret_cast<unsigned short*>(&t);
}

// ---------------------------------------------------------------------------
// Kernel 0: fold weights. Wcomb[f][j] = sum_c W_emb[f][c]*Wcat[c][j]
// j: [0,128)=Q (h=j>>5,k=j&31), [128,256)=K, [256,320)=V0
// ---------------------------------------------------------------------------
__global__ __launch_bounds__(256) void fold_weights(
    const float* __restrict__ W_emb, const float* __restrict__ b_emb,
    const float* __restrict__ Wq, const float* __restrict__ Wk,
    const float* __restrict__ Wv0,
    float* __restrict__ Wcomb, float* __restrict__ bcomb)
{
    int idx = blockIdx.x * 256 + threadIdx.x;
    if (idx >= 33 * 320) return;
    int row = idx / 320, j = idx - row * 320;
    float acc = 0.f;
    for (int c = 0; c < 64; ++c) {
        float w;
        if (j < 128)      { int h = j >> 5,         k = j & 31;         w = Wq [(h * 64 + c) * 32 + k]; }
        else if (j < 256) { int h = (j - 128) >> 5, k = (j - 128) & 31; w = Wk [(h * 64 + c) * 32 + k]; }
        else              { int h = (j - 256) >> 4, v = (j - 256) & 15; w = Wv0[(h * 64 + c) * 16 + v]; }
        float lhs = (row < 32) ? W_emb[row * 64 + c] : b_emb[c];
        acc += lhs * w;
    }
    if (row < 32) Wcomb[row * 320 + j] = acc;
    else          bcomb[j] = acc;
}

// ---------------------------------------------------------------------------
// Kernel 1: per-node tables.
//   Qtab[n][128] f32
//   KVt[n] record of 96 u32-slots (384B): [0..64) u32 = half2(k_j, k_j+16)
//   at lane h*16+j; [64..96) = 64 u16 f16 V at lane h*16+j.
// ---------------------------------------------------------------------------
__global__ __launch_bounds__(256) void node_qkv(
    const float* __restrict__ nf, const float* __restrict__ Wcomb,
    const float* __restrict__ bcomb, float* __restrict__ Qtab,
    unsigned* __restrict__ KVt, int Nn)
{
    int c    = blockIdx.x % 10;
    int tile = blockIdx.x / 10;
    __shared__ float sW[32][32];
    __shared__ float sb[32];
    for (int i = threadIdx.x; i < 1024; i += 256) {
        int f = i >> 5, j = i & 31;
        sW[f][j] = Wcomb[f * 320 + c * 32 + j];
    }
    if (threadIdx.x < 32) sb[threadIdx.x] = bcomb[c * 32 + threadIdx.x];
    __syncthreads();
    int n = tile * 256 + threadIdx.x;
    if (n >= Nn) return;

    float nfv[32];
    const float4* nfp = (const float4*)(nf + (size_t)n * 32);
#pragma unroll
    for (int f4 = 0; f4 < 8; ++f4) {
        float4 v = nfp[f4];
        nfv[f4 * 4 + 0] = v.x; nfv[f4 * 4 + 1] = v.y;
        nfv[f4 * 4 + 2] = v.z; nfv[f4 * 4 + 3] = v.w;
    }
    float acc[32];
#pragma unroll
    for (int j = 0; j < 32; ++j) acc[j] = sb[j];
#pragma unroll
    for (int f = 0; f < 32; ++f) {
        float x = nfv[f];
#pragma unroll
        for (int j4 = 0; j4 < 8; ++j4) {
            float4 w = *(const float4*)&sW[f][j4 * 4];
            acc[j4 * 4 + 0] += x * w.x; acc[j4 * 4 + 1] += x * w.y;
            acc[j4 * 4 + 2] += x * w.z; acc[j4 * 4 + 3] += x * w.w;
        }
    }
    if (c < 4) {
        float4* outp = (float4*)(Qtab + (size_t)n * 128 + c * 32);
#pragma unroll
        for (int j4 = 0; j4 < 8; ++j4) {
            float4 v;
            v.x = acc[j4 * 4 + 0]; v.y = acc[j4 * 4 + 1];
            v.z = acc[j4 * 4 + 2]; v.w = acc[j4 * 4 + 3];
            outp[j4] = v;
        }
    } else if (c < 8) {
        unsigned* kp = KVt + (size_t)n * 96 + (c - 4) * 16;
#pragma unroll
        for (int j = 0; j < 16; ++j) kp[j] = pack_h2(acc[j], acc[j + 16]);
    } else {
        unsigned short* vp = (unsigned short*)(KVt + (size_t)n * 96 + 64) + (c - 8) * 32;
#pragma unroll
        for (int j = 0; j < 32; ++j) vp[j] = pack_h1(acc[j]);
    }
}

// ---------------------------------------------------------------------------
// Kernel 2: degree count
// ---------------------------------------------------------------------------
__global__ __launch_bounds__(256) void count_deg(
    const int* __restrict__ ei, int* __restrict__ deg, int Ee)
{
    int e = blockIdx.x * 256 + threadIdx.x;
    if (e >= Ee) return;
    atomicAdd(&deg[ei[Ee + e]], 1);
}

// ---------------------------------------------------------------------------
// Kernel 3: offsets via wave prefix-sum + one atomic per wave (order-free).
// ---------------------------------------------------------------------------
__global__ __launch_bounds__(256) void calc_offs(
    const int* __restrict__ deg, int* __restrict__ offs,
    int* __restrict__ cursor, int* __restrict__ gtot, int Nn)
{
    int n = blockIdx.x * 256 + threadIdx.x;
    int lane = threadIdx.x & 63;
    int d = (n < Nn) ? deg[n] : 0;
    int pre = d;
#pragma unroll
    for (int s = 1; s < 64; s <<= 1) {
        int t = __shfl_up(pre, s);
        if (lane >= s) pre += t;
    }
    int waveTot = __shfl(pre, 63);
    int base = 0;
    if (lane == 63) base = atomicAdd(gtot, waveTot);
    base = __shfl(base, 63);
    if (n < Nn) {
        int off = base + pre - d;
        offs[n] = off; cursor[n] = off;
    }
}

// ---------------------------------------------------------------------------
// Kernel 4: scatter edges into CSR-by-dst; pack (src, d) as int2.
// ---------------------------------------------------------------------------
__global__ __launch_bounds__(256) void scatter_edges(
    const float* __restrict__ pos, const int* __restrict__ ei,
    int* __restrict__ cursor, int2* __restrict__ csr, int Ee)
{
    int e = blockIdx.x * 256 + threadIdx.x;
    if (e >= Ee) return;
    int s  = ei[e];
    int dg = ei[Ee + e];
    float dx = pos[(size_t)dg * 3 + 0] - pos[(size_t)s * 3 + 0];
    float dy = pos[(size_t)dg * 3 + 1] - pos[(size_t)s * 3 + 1];
    float dz = pos[(size_t)dg * 3 + 2] - pos[(size_t)s * 3 + 2];
    float d = sqrtf(dx * dx + dy * dy + dz * dz) + 1e-8f;
    int p = atomicAdd(&cursor[dg], 1);
    int2 pk; pk.x = s; pk.y = __float_as_int(d);
    csr[p] = pk;
}

// ---------------------------------------------------------------------------
// Kernel 5a: edge-parallel radial MLP, materialized to f16.
//   RKT[e][lane] = half2(rk[h][j], rk[h][j+16]); RVT[e][lane] = f16 rv[h][j]
// R1/b1/R2/b2 accessed with uniform indices -> scalar loads.
// ---------------------------------------------------------------------------
__global__ __launch_bounds__(256) void radial_mlp(
    const int2* __restrict__ csr,
    const float* __restrict__ R1, const float* __restrict__ b1,
    const float* __restrict__ R2, const float* __restrict__ b2,
    unsigned* __restrict__ RKT, unsigned short* __restrict__ RVT, int Ee)
{
    int p = blockIdx.x * 256 + threadIdx.x;
    if (p >= Ee) return;
    float d = __int_as_float(csr[p].y);
#pragma unroll
    for (int h = 0; h < 4; ++h) {
        float rh[16];
#pragma unroll
        for (int r = 0; r < 16; ++r) {
            float x = fmaf(d, R1[h * 16 + r], b1[h * 16 + r]);
            rh[r] = x / (1.f + __expf(-x));
        }
        float a[48];
#pragma unroll
        for (int c = 0; c < 48; ++c) a[c] = b2[h * 64 + c];
#pragma unroll
        for (int r = 0; r < 16; ++r) {
            const float* row = R2 + (size_t)(h * 16 + r) * 64;
#pragma unroll
            for (int c = 0; c < 48; ++c) a[c] = fmaf(rh[r], row[c], a[c]);
        }
        unsigned* kp = RKT + (size_t)p * 64 + h * 16;
#pragma unroll
        for (int j = 0; j < 16; ++j) kp[j] = pack_h2(a[j], a[j + 16]);
        unsigned short* vp = RVT + (size_t)p * 64 + h * 16;
#pragma unroll
        for (int j = 0; j < 16; ++j) vp[j] = pack_h1(a[32 + j]);
    }
}

// ---------------------------------------------------------------------------
// Kernel 6a: attention with materialized radial. One wave per node.
// Lane: h=lane>>4, j=lane&15. ~30 VALU ops/edge; 1-edge prefetch.
// ---------------------------------------------------------------------------
__global__ __launch_bounds__(256) void node_attn_mat(
    const float* __restrict__ Qtab, const unsigned* __restrict__ KVt,
    const unsigned* __restrict__ RKT, const unsigned short* __restrict__ RVT,
    const int2* __restrict__ csr, const int* __restrict__ offs,
    const int* __restrict__ deg, const int* __restrict__ batch,
    float* __restrict__ pooled, int Nn)
{
    int lane = threadIdx.x & 63;
    int h = lane >> 4, j = lane & 15;
    int n = __builtin_amdgcn_readfirstlane(blockIdx.x * 4 + (threadIdx.x >> 6));
    if (n >= Nn) return;
    int start = offs[n], cnt = deg[n];
    if (cnt == 0) return;

    float q0 = Qtab[(size_t)n * 128 + h * 32 + j];
    float q1 = Qtab[(size_t)n * 128 + h * 32 + j + 16];
    float m = -3.0e38f, l = 0.f, acc = 0.f;
    const float rs = 0.17677669529663687f;

    int end = start + cnt;
    int src0 = csr[start].x;
    unsigned       ku  = KVt[(size_t)src0 * 96 + lane];
    unsigned short vu  = ((const unsigned short*)(KVt + (size_t)src0 * 96 + 64))[lane];
    unsigned       rku = RKT[(size_t)start * 64 + lane];
    unsigned short rvu = RVT[(size_t)start * 64 + lane];

    for (int e = start; e < end; ++e) {
        unsigned ku_n = ku; unsigned short vu_n = vu;
        unsigned rku_n = rku; unsigned short rvu_n = rvu;
        if (e + 1 < end) {
            int s2 = csr[e + 1].x;
            ku_n  = KVt[(size_t)s2 * 96 + lane];
            vu_n  = ((const unsigned short*)(KVt + (size_t)s2 * 96 + 64))[lane];
            rku_n = RKT[((size_t)e + 1) * 64 + lane];
            rvu_n = RVT[((size_t)e + 1) * 64 + lane];
        }
        __half2 kh  = *reinterpret_cast<__half2*>(&ku);
        __half2 rkh = *reinterpret_cast<__half2*>(&rku);
        float kx  = __half2float(__low2half(kh)),  ky  = __half2float(__high2half(kh));
        float rkx = __half2float(__low2half(rkh)), rky = __half2float(__high2half(rkh));
        float vv  = __half2float(*reinterpret_cast<__half*>(&vu));
        float rvf = __half2float(*reinterpret_cast<__half*>(&rvu));
        float p = q0 * kx * rkx + q1 * ky * rky;
        p += __shfl_xor(p, 1);
        p += __shfl_xor(p, 2);
        p += __shfl_xor(p, 4);
        p += __shfl_xor(p, 8);
        float sc  = p * rs;
        float mn  = fmaxf(m, sc);
        float sca = __expf(m - mn);
        float ex  = __expf(sc - mn);
        l   = fmaf(l, sca, ex);
        acc = fmaf(acc, sca, ex * (vv * rvf));
        m = mn;
        ku = ku_n; vu = vu_n; rku = rku_n; rvu = rvu_n;
    }
    float o = acc / (l + 1e-9f);
    atomicAdd(&pooled[(size_t)batch[n] * 64 + lane], o);
}

// ---------------------------------------------------------------------------
// Kernel 6b: fallback — recompute radial in-loop (shfl broadcast, v2f pk-fma).
// ---------------------------------------------------------------------------
__global__ __launch_bounds__(256) void node_attn_rec(
    const float* __restrict__ Qtab, const unsigned* __restrict__ KVt,
    const int2* __restrict__ csr, const int* __restrict__ offs,
    const int* __restrict__ deg, const int* __restrict__ batch,
    const float* __restrict__ R1, const float* __restrict__ b1,
    const float* __restrict__ R2, const float* __restrict__ b2,
    float* __restrict__ pooled, int Nn)
{
    int lane = threadIdx.x & 63;
    int h = lane >> 4, j = lane & 15;
    int hb = h << 4;
    int n = __builtin_amdgcn_readfirstlane(blockIdx.x * 4 + (threadIdx.x >> 6));
    if (n >= Nn) return;
    int start = offs[n], cnt = deg[n];
    if (cnt == 0) return;

    v2f c01[16]; float c2[16];
#pragma unroll
    for (int r = 0; r < 16; ++r) {
        const float* row = R2 + (size_t)(h * 16 + r) * 64;
        v2f t; t.x = row[j]; t.y = row[j + 16];
        c01[r] = t; c2[r] = row[32 + j];
    }
    float r1l = R1[lane], b1l = b1[lane];
    v2f bk; bk.x = b2[h * 64 + j]; bk.y = b2[h * 64 + j + 16];
    float bv = b2[h * 64 + 32 + j];
    const float rs = 0.17677669529663687f;

    float q0 = Qtab[(size_t)n * 128 + h * 32 + j];
    float q1 = Qtab[(size_t)n * 128 + h * 32 + j + 16];
    float m = -3.0e38f, l = 0.f, acc = 0.f;

    int end = start + cnt;
    int2 pk = csr[start];
    unsigned       ku = KVt[(size_t)pk.x * 96 + lane];
    unsigned short vu = ((const unsigned short*)(KVt + (size_t)pk.x * 96 + 64))[lane];

    for (int e = start; e < end; ++e) {
        int2 pk_n = pk; unsigned ku_n = ku; unsigned short vu_n = vu;
        if (e + 1 < end) {
            pk_n = csr[e + 1];
            ku_n = KVt[(size_t)pk_n.x * 96 + lane];
            vu_n = ((const unsigned short*)(KVt + (size_t)pk_n.x * 96 + 64))[lane];
        }
        float d = __int_as_float(pk.y);
        float x = fmaf(d, r1l, b1l);
        float rhv = x / (1.f + __expf(-x));
        v2f rk = bk; float rv = bv;
#pragma unroll
        for (int r = 0; r < 16; ++r) {
            float rr = __shfl(rhv, hb + r);
            rk += c01[r] * rr;
            rv = fmaf(rr, c2[r], rv);
        }
        __half2 kh = *reinterpret_cast<__half2*>(&ku);
        float kx = __half2float(__low2half(kh)), ky = __half2float(__high2half(kh));
        float vv = __half2float(*reinterpret_cast<__half*>(&vu));
        float p = q0 * kx * rk.x + q1 * ky * rk.y;
        p += __shfl_xor(p, 1);
        p += __shfl_xor(p, 2);
        p += __shfl_xor(p, 4);
        p += __shfl_xor(p, 8);
        float sc  = p * rs;
        float mn  = fmaxf(m, sc);
        float sca = __expf(m - mn);
        float ex  = __expf(sc - mn);
        l   = fmaf(l, sca, ex);
        acc = fmaf(acc, sca, ex * (vv * rv));
        m = mn;
        pk = pk_n; ku = ku_n; vu = vu_n;
    }
    float o = acc / (l + 1e-9f);
    atomicAdd(&pooled[(size_t)batch[n] * 64 + lane], o);
}

// ---------------------------------------------------------------------------
// Kernel 7: out[b][o] = sum_i pooled[b][i] * Wproj[i][o]
// ---------------------------------------------------------------------------
__global__ __launch_bounds__(256) void final_proj(
    const float* __restrict__ pooled, const float* __restrict__ Wproj,
    float* __restrict__ out, int total)
{
    int idx = blockIdx.x * 256 + threadIdx.x;
    if (idx >= total) return;
    int b = idx >> 6, o = idx & 63;
    float acc = 0.f;
#pragma unroll
    for (int i = 0; i < 64; ++i) acc += pooled[b * 64 + i] * Wproj[i * 64 + o];
    out[idx] = acc;
}

extern "C" void kernel_launch(void* const* d_in, const int* in_sizes, int n_in,
                              void* d_out, int out_size, void* d_ws, size_t ws_size,
                              hipStream_t stream)
{
    const float* pos   = (const float*)d_in[0];
    const float* nf    = (const float*)d_in[1];
    const int*   ei    = (const int*)d_in[2];
    const int*   batch = (const int*)d_in[3];
    const float* W_emb = (const float*)d_in[4];
    const float* b_emb = (const float*)d_in[5];
    const float* Wq    = (const float*)d_in[6];
    const float* Wk    = (const float*)d_in[7];
    const float* Wv0   = (const float*)d_in[8];
    const float* R1    = (const float*)d_in[10];
    const float* b1    = (const float*)d_in[11];
    const float* R2    = (const float*)d_in[12];
    const float* b2    = (const float*)d_in[13];
    const float* Wproj = (const float*)d_in[14];
    float* out = (float*)d_out;

    long Nn = in_sizes[0] / 3;
    long Ee = in_sizes[2] / 2;
    int  Bb = out_size / 64;

    float* ws = (float*)d_ws;
    size_t o = 0;
    size_t WCOMB = o; o += 32 * 320;
    size_t BCOMB = o; o += 320;
    size_t QTAB  = o; o += (size_t)Nn * 128;
    size_t KVT   = o; o += (size_t)Nn * 96;
    size_t DEG   = o; o += (size_t)Nn;
    size_t GTOT  = o; o += 2;
    size_t POOL  = o; o += (size_t)Bb * 64;
    size_t OFFS  = o; o += (size_t)Nn;
    size_t CURS  = o; o += (size_t)Nn;
    o = (o + 1) & ~(size_t)1;           // 8B-align csr
    size_t CSR   = o; o += (size_t)Ee * 2;
    size_t RKT   = o; o += (size_t)Ee * 64;
    size_t RVT   = o; o += (size_t)Ee * 32;
    bool use_mat = (ws_size >= o * sizeof(float));

    hipMemsetAsync(ws + DEG, 0,
                   ((size_t)Nn + 2 + (size_t)Bb * 64) * sizeof(float), stream);

    fold_weights<<<idiv_up(33 * 320, 256), 256, 0, stream>>>(
        W_emb, b_emb, Wq, Wk, Wv0, ws + WCOMB, ws + BCOMB);

    node_qkv<<<idiv_up(Nn, 256) * 10, 256, 0, stream>>>(
        nf, ws + WCOMB, ws + BCOMB, ws + QTAB, (unsigned*)(ws + KVT), (int)Nn);

    count_deg<<<idiv_up(Ee, 256), 256, 0, stream>>>(
        ei, (int*)(ws + DEG), (int)Ee);

    calc_offs<<<idiv_up(Nn, 256), 256, 0, stream>>>(
        (const int*)(ws + DEG), (int*)(ws + OFFS), (int*)(ws + CURS),
        (int*)(ws + GTOT), (int)Nn);

    scatter_edges<<<idiv_up(Ee, 256), 256, 0, stream>>>(
        pos, ei, (int*)(ws + CURS), (int2*)(ws + CSR), (int)Ee);

    if (use_mat) {
        radial_mlp<<<idiv_up(Ee, 256), 256, 0, stream>>>(
            (const int2*)(ws + CSR), R1, b1, R2, b2,
            (unsigned*)(ws + RKT), (unsigned short*)(ws + RVT), (int)Ee);

        node_attn_mat<<<idiv_up(Nn, 4), 256, 0, stream>>>(
            ws + QTAB, (const unsigned*)(ws + KVT),
            (const unsigned*)(ws + RKT), (const unsigned short*)(ws + RVT),
            (const int2*)(ws + CSR), (const int*)(ws + OFFS),
            (const int*)(ws + DEG), batch, ws + POOL, (int)Nn);
    } else {
        node_attn_rec<<<idiv_up(Nn, 4), 256, 0, stream>>>(
            ws + QTAB, (const unsigned*)(ws + KVT),
            (const int2*)(ws + CSR), (const int*)(ws + OFFS),
            (const int*)(ws + DEG), batch,
            R1, b1, R2, b2, ws + POOL, (int)Nn);
    }

    final_proj<<<idiv_up(out_size, 256), 256, 0, stream>>>(
        ws + POOL, Wproj, out, out_size);
}

// Round 6
// 315.211 us; speedup vs baseline: 1.5891x; 1.3328x over previous
//
#include <hip/hip_runtime.h>
#include <hip/hip_fp16.h>

static inline int idiv_up(long a, long b) { return (int)((a + b - 1) / b); }

__device__ __forceinline__ unsigned pack_h2(float a, float b) {
    __half2 t = __floats2half2_rn(a, b);
    return *reinterpret_cast<unsigned*>(&t);
}
__device__ __forceinline__ unsigned short pack_h1(float a) {
    __half t = __float2half_rn(a);
    return *reinterpret_cast<unsigned short*>(&t);
}
__device__ __forceinline__ void unp_h2(unsigned u, float& lo, float& hi) {
    __half2 t = *reinterpret_cast<__half2*>(&u);
    lo = __half2float(__low2half(t));
    hi = __half2float(__high2half(t));
}
__device__ __forceinline__ float unp_h1(unsigned short u) {
    return __half2float(*reinterpret_cast<__half*>(&u));
}

// DPP cross-lane on the VALU pipe (no DS traffic).
// 0xB1 = quad_perm[1,0,3,2] (xor1), 0x4E = quad_perm[2,3,0,1] (xor2),
// 0x121/0x124/0x128 = row_ror:1/4/8 (lane i reads lane (i-N)&15).
template <int CTRL>
__device__ __forceinline__ float dppf(float x) {
    return __int_as_float(__builtin_amdgcn_update_dpp(
        0, __float_as_int(x), CTRL, 0xF, 0xF, true));
}
// all-lane sum within each 16-lane row
__device__ __forceinline__ float row_allsum(float p) {
    p += dppf<0xB1>(p);
    p += dppf<0x4E>(p);
    p += dppf<0x124>(p);
    p += dppf<0x128>(p);
    return p;
}

// ---------------------------------------------------------------------------
// Kernel 0: fold weights. Wcomb[f][j] = sum_c W_emb[f][c]*Wcat[c][j]
// j: [0,128)=Q (h=j>>5,k=j&31), [128,256)=K, [256,320)=V0
// ---------------------------------------------------------------------------
__global__ __launch_bounds__(256) void fold_weights(
    const float* __restrict__ W_emb, const float* __restrict__ b_emb,
    const float* __restrict__ Wq, const float* __restrict__ Wk,
    const float* __restrict__ Wv0,
    float* __restrict__ Wcomb, float* __restrict__ bcomb)
{
    int idx = blockIdx.x * 256 + threadIdx.x;
    if (idx >= 33 * 320) return;
    int row = idx / 320, j = idx - row * 320;
    float acc = 0.f;
    for (int c = 0; c < 64; ++c) {
        float w;
        if (j < 128)      { int h = j >> 5,         k = j & 31;         w = Wq [(h * 64 + c) * 32 + k]; }
        else if (j < 256) { int h = (j - 128) >> 5, k = (j - 128) & 31; w = Wk [(h * 64 + c) * 32 + k]; }
        else              { int h = (j - 256) >> 4, v = (j - 256) & 15; w = Wv0[(h * 64 + c) * 16 + v]; }
        float lhs = (row < 32) ? W_emb[row * 64 + c] : b_emb[c];
        acc += lhs * w;
    }
    if (row < 32) Wcomb[row * 320 + j] = acc;
    else          bcomb[j] = acc;
}

// ---------------------------------------------------------------------------
// Kernel 1: per-node tables.
//   Qtab[n][128] f32
//   KVt[n]: 96 u32 slots (384B): [0..64) = half2(k_j,k_j+16) at lane h*16+j;
//   [64..96) = 64 u16 f16 V at lane h*16+j.
// ---------------------------------------------------------------------------
__global__ __launch_bounds__(256) void node_qkv(
    const float* __restrict__ nf, const float* __restrict__ Wcomb,
    const float* __restrict__ bcomb, float* __restrict__ Qtab,
    unsigned* __restrict__ KVt, int Nn)
{
    int c    = blockIdx.x % 10;
    int tile = blockIdx.x / 10;
    __shared__ float sW[32][32];
    __shared__ float sb[32];
    for (int i = threadIdx.x; i < 1024; i += 256) {
        int f = i >> 5, j = i & 31;
        sW[f][j] = Wcomb[f * 320 + c * 32 + j];
    }
    if (threadIdx.x < 32) sb[threadIdx.x] = bcomb[c * 32 + threadIdx.x];
    __syncthreads();
    int n = tile * 256 + threadIdx.x;
    if (n >= Nn) return;

    float nfv[32];
    const float4* nfp = (const float4*)(nf + (size_t)n * 32);
#pragma unroll
    for (int f4 = 0; f4 < 8; ++f4) {
        float4 v = nfp[f4];
        nfv[f4 * 4 + 0] = v.x; nfv[f4 * 4 + 1] = v.y;
        nfv[f4 * 4 + 2] = v.z; nfv[f4 * 4 + 3] = v.w;
    }
    float acc[32];
#pragma unroll
    for (int j = 0; j < 32; ++j) acc[j] = sb[j];
#pragma unroll
    for (int f = 0; f < 32; ++f) {
        float x = nfv[f];
#pragma unroll
        for (int j4 = 0; j4 < 8; ++j4) {
            float4 w = *(const float4*)&sW[f][j4 * 4];
            acc[j4 * 4 + 0] += x * w.x; acc[j4 * 4 + 1] += x * w.y;
            acc[j4 * 4 + 2] += x * w.z; acc[j4 * 4 + 3] += x * w.w;
        }
    }
    if (c < 4) {
        float4* outp = (float4*)(Qtab + (size_t)n * 128 + c * 32);
#pragma unroll
        for (int j4 = 0; j4 < 8; ++j4) {
            float4 v;
            v.x = acc[j4 * 4 + 0]; v.y = acc[j4 * 4 + 1];
            v.z = acc[j4 * 4 + 2]; v.w = acc[j4 * 4 + 3];
            outp[j4] = v;
        }
    } else if (c < 8) {
        unsigned* kp = KVt + (size_t)n * 96 + (c - 4) * 16;
#pragma unroll
        for (int j = 0; j < 16; ++j) kp[j] = pack_h2(acc[j], acc[j + 16]);
    } else {
        unsigned short* vp = (unsigned short*)(KVt + (size_t)n * 96 + 64) + (c - 8) * 32;
#pragma unroll
        for (int j = 0; j < 32; ++j) vp[j] = pack_h1(acc[j]);
    }
}

// ---------------------------------------------------------------------------
// Kernel 2: degree count
// ---------------------------------------------------------------------------
__global__ __launch_bounds__(256) void count_deg(
    const int* __restrict__ ei, int* __restrict__ deg, int Ee)
{
    int e = blockIdx.x * 256 + threadIdx.x;
    if (e >= Ee) return;
    atomicAdd(&deg[ei[Ee + e]], 1);
}

// ---------------------------------------------------------------------------
// Kernel 3: offsets via wave prefix-sum + one atomic per wave (order-free).
// ---------------------------------------------------------------------------
__global__ __launch_bounds__(256) void calc_offs(
    const int* __restrict__ deg, int* __restrict__ offs,
    int* __restrict__ cursor, int* __restrict__ gtot, int Nn)
{
    int n = blockIdx.x * 256 + threadIdx.x;
    int lane = threadIdx.x & 63;
    int d = (n < Nn) ? deg[n] : 0;
    int pre = d;
#pragma unroll
    for (int s = 1; s < 64; s <<= 1) {
        int t = __shfl_up(pre, s);
        if (lane >= s) pre += t;
    }
    int waveTot = __shfl(pre, 63);
    int base = 0;
    if (lane == 63) base = atomicAdd(gtot, waveTot);
    base = __shfl(base, 63);
    if (n < Nn) {
        int off = base + pre - d;
        offs[n] = off; cursor[n] = off;
    }
}

// ---------------------------------------------------------------------------
// Kernel 4: scatter edges into CSR-by-dst; pack (src, d) as int2.
// ---------------------------------------------------------------------------
__global__ __launch_bounds__(256) void scatter_edges(
    const float* __restrict__ pos, const int* __restrict__ ei,
    int* __restrict__ cursor, int2* __restrict__ csr, int Ee)
{
    int e = blockIdx.x * 256 + threadIdx.x;
    if (e >= Ee) return;
    int s  = ei[e];
    int dg = ei[Ee + e];
    float dx = pos[(size_t)dg * 3 + 0] - pos[(size_t)s * 3 + 0];
    float dy = pos[(size_t)dg * 3 + 1] - pos[(size_t)s * 3 + 1];
    float dz = pos[(size_t)dg * 3 + 2] - pos[(size_t)s * 3 + 2];
    float d = sqrtf(dx * dx + dy * dy + dz * dz) + 1e-8f;
    int p = atomicAdd(&cursor[dg], 1);
    int2 pk; pk.x = s; pk.y = __float_as_int(d);
    csr[p] = pk;
}

// ---------------------------------------------------------------------------
// Kernel 5: fused per-node attention — DS-free inner loop (all DPP).
// One wave per node. Lane: h=lane>>4, j=lane&15.
// rh lives at lane (h,r=j); rotated with row_ror:1; weights pre-permuted
// diagonally so step t multiplies R2 row (j-t)&15.
// ---------------------------------------------------------------------------
__global__ __launch_bounds__(256) void node_attn(
    const float* __restrict__ Qtab, const unsigned* __restrict__ KVt,
    const int2* __restrict__ csr, const int* __restrict__ offs,
    const int* __restrict__ deg, const int* __restrict__ batch,
    const float* __restrict__ R1, const float* __restrict__ b1,
    const float* __restrict__ R2, const float* __restrict__ b2,
    float* __restrict__ pooled, int Nn)
{
    int lane = threadIdx.x & 63;
    int h = lane >> 4, j = lane & 15;
    int n = __builtin_amdgcn_readfirstlane(blockIdx.x * 4 + (threadIdx.x >> 6));
    if (n >= Nn) return;
    int start = offs[n], cnt = deg[n];
    if (cnt == 0) return;

    // diagonally permuted R2 columns: cwX[t] = col X at row (j-t)&15
    float cw0[16], cw1[16], cw2[16];
#pragma unroll
    for (int t = 0; t < 16; ++t) {
        int r = (j - t) & 15;
        const float* row = R2 + (size_t)(h * 16 + r) * 64;
        cw0[t] = row[j]; cw1[t] = row[j + 16]; cw2[t] = row[32 + j];
    }
    float r1l = R1[lane], b1l = b1[lane];
    float bk0 = b2[h * 64 + j], bk1 = b2[h * 64 + j + 16], bv = b2[h * 64 + 32 + j];
    const float rs = 0.17677669529663687f; // 1/sqrt(32)

    float q0 = Qtab[(size_t)n * 128 + h * 32 + j];
    float q1 = Qtab[(size_t)n * 128 + h * 32 + j + 16];
    float m = -3.0e38f, l = 0.f, acc = 0.f;

    int e = start, end = start + cnt;
    int2 pk0, pk1; unsigned ku0 = 0, ku1 = 0; unsigned short vu0 = 0, vu1 = 0;
    if (e + 1 < end) {
        pk0 = csr[e]; pk1 = csr[e + 1];
        ku0 = KVt[(size_t)pk0.x * 96 + lane];
        vu0 = ((const unsigned short*)(KVt + (size_t)pk0.x * 96 + 64))[lane];
        ku1 = KVt[(size_t)pk1.x * 96 + lane];
        vu1 = ((const unsigned short*)(KVt + (size_t)pk1.x * 96 + 64))[lane];
    }
    for (; e + 1 < end; e += 2) {
        int2 cpk0 = pk0, cpk1 = pk1;
        unsigned cku0 = ku0, cku1 = ku1;
        unsigned short cvu0 = vu0, cvu1 = vu1;
        if (e + 3 < end) {
            pk0 = csr[e + 2]; pk1 = csr[e + 3];
            ku0 = KVt[(size_t)pk0.x * 96 + lane];
            vu0 = ((const unsigned short*)(KVt + (size_t)pk0.x * 96 + 64))[lane];
            ku1 = KVt[(size_t)pk1.x * 96 + lane];
            vu1 = ((const unsigned short*)(KVt + (size_t)pk1.x * 96 + 64))[lane];
        }
        float d0 = __int_as_float(cpk0.y), d1 = __int_as_float(cpk1.y);
        float x0 = fmaf(d0, r1l, b1l),     x1 = fmaf(d1, r1l, b1l);
        float rc0 = x0 * __builtin_amdgcn_rcpf(1.f + __expf(-x0));
        float rc1 = x1 * __builtin_amdgcn_rcpf(1.f + __expf(-x1));
        float rk00 = bk0, rk01 = bk1, rv0 = bv;
        float rk10 = bk0, rk11 = bk1, rv1 = bv;
#pragma unroll
        for (int t = 0; t < 16; ++t) {
            if (t) { rc0 = dppf<0x121>(rc0); rc1 = dppf<0x121>(rc1); }
            rk00 = fmaf(rc0, cw0[t], rk00);
            rk01 = fmaf(rc0, cw1[t], rk01);
            rv0  = fmaf(rc0, cw2[t], rv0);
            rk10 = fmaf(rc1, cw0[t], rk10);
            rk11 = fmaf(rc1, cw1[t], rk11);
            rv1  = fmaf(rc1, cw2[t], rv1);
        }
        float kx0, ky0, kx1, ky1;
        unp_h2(cku0, kx0, ky0);
        unp_h2(cku1, kx1, ky1);
        float p0 = q0 * kx0 * rk00 + q1 * ky0 * rk01;
        float p1 = q0 * kx1 * rk10 + q1 * ky1 * rk11;
        p0 = row_allsum(p0);
        p1 = row_allsum(p1);
        float sc0 = p0 * rs, sc1 = p1 * rs;
        float mn  = fmaxf(m, fmaxf(sc0, sc1));
        float sca = __expf(m - mn);
        float ex0 = __expf(sc0 - mn);
        float ex1 = __expf(sc1 - mn);
        l = fmaf(l, sca, ex0 + ex1);
        float w0 = unp_h1(cvu0) * rv0;
        float w1 = unp_h1(cvu1) * rv1;
        acc = fmaf(acc, sca, fmaf(ex0, w0, ex1 * w1));
        m = mn;
    }
    if (e < end) {
        int2 pk = csr[e];
        unsigned       ku = KVt[(size_t)pk.x * 96 + lane];
        unsigned short vu = ((const unsigned short*)(KVt + (size_t)pk.x * 96 + 64))[lane];
        float d = __int_as_float(pk.y);
        float x = fmaf(d, r1l, b1l);
        float rc = x * __builtin_amdgcn_rcpf(1.f + __expf(-x));
        float rk0 = bk0, rk1 = bk1, rv = bv;
#pragma unroll
        for (int t = 0; t < 16; ++t) {
            if (t) rc = dppf<0x121>(rc);
            rk0 = fmaf(rc, cw0[t], rk0);
            rk1 = fmaf(rc, cw1[t], rk1);
            rv  = fmaf(rc, cw2[t], rv);
        }
        float kx, ky;
        unp_h2(ku, kx, ky);
        float p = q0 * kx * rk0 + q1 * ky * rk1;
        p = row_allsum(p);
        float sc  = p * rs;
        float mn  = fmaxf(m, sc);
        float sca = __expf(m - mn);
        float ex  = __expf(sc - mn);
        l   = fmaf(l, sca, ex);
        acc = fmaf(acc, sca, ex * (unp_h1(vu) * rv));
        m = mn;
    }
    float o = acc / (l + 1e-9f);
    atomicAdd(&pooled[(size_t)batch[n] * 64 + lane], o);
}

// ---------------------------------------------------------------------------
// Kernel 6: out[b][o] = sum_i pooled[b][i] * Wproj[i][o]
// ---------------------------------------------------------------------------
__global__ __launch_bounds__(256) void final_proj(
    const float* __restrict__ pooled, const float* __restrict__ Wproj,
    float* __restrict__ out, int total)
{
    int idx = blockIdx.x * 256 + threadIdx.x;
    if (idx >= total) return;
    int b = idx >> 6, o = idx & 63;
    float acc = 0.f;
#pragma unroll
    for (int i = 0; i < 64; ++i) acc += pooled[b * 64 + i] * Wproj[i * 64 + o];
    out[idx] = acc;
}

extern "C" void kernel_launch(void* const* d_in, const int* in_sizes, int n_in,
                              void* d_out, int out_size, void* d_ws, size_t ws_size,
                              hipStream_t stream)
{
    const float* pos   = (const float*)d_in[0];
    const float* nf    = (const float*)d_in[1];
    const int*   ei    = (const int*)d_in[2];
    const int*   batch = (const int*)d_in[3];
    const float* W_emb = (const float*)d_in[4];
    const float* b_emb = (const float*)d_in[5];
    const float* Wq    = (const float*)d_in[6];
    const float* Wk    = (const float*)d_in[7];
    const float* Wv0   = (const float*)d_in[8];
    const float* R1    = (const float*)d_in[10];
    const float* b1    = (const float*)d_in[11];
    const float* R2    = (const float*)d_in[12];
    const float* b2    = (const float*)d_in[13];
    const float* Wproj = (const float*)d_in[14];
    float* out = (float*)d_out;

    long Nn = in_sizes[0] / 3;
    long Ee = in_sizes[2] / 2;
    int  Bb = out_size / 64;

    float* ws = (float*)d_ws;
    size_t o = 0;
    size_t WCOMB = o; o += 32 * 320;
    size_t BCOMB = o; o += 320;
    size_t QTAB  = o; o += (size_t)Nn * 128;
    size_t KVT   = o; o += (size_t)Nn * 96;
    size_t DEG   = o; o += (size_t)Nn;
    size_t GTOT  = o; o += 2;
    size_t POOL  = o; o += (size_t)Bb * 64;
    size_t OFFS  = o; o += (size_t)Nn;
    size_t CURS  = o; o += (size_t)Nn;
    o = (o + 1) & ~(size_t)1;           // 8B-align csr
    size_t CSR   = o; o += (size_t)Ee * 2;

    hipMemsetAsync(ws + DEG, 0,
                   ((size_t)Nn + 2 + (size_t)Bb * 64) * sizeof(float), stream);

    fold_weights<<<idiv_up(33 * 320, 256), 256, 0, stream>>>(
        W_emb, b_emb, Wq, Wk, Wv0, ws + WCOMB, ws + BCOMB);

    node_qkv<<<idiv_up(Nn, 256) * 10, 256, 0, stream>>>(
        nf, ws + WCOMB, ws + BCOMB, ws + QTAB, (unsigned*)(ws + KVT), (int)Nn);

    count_deg<<<idiv_up(Ee, 256), 256, 0, stream>>>(
        ei, (int*)(ws + DEG), (int)Ee);

    calc_offs<<<idiv_up(Nn, 256), 256, 0, stream>>>(
        (const int*)(ws + DEG), (int*)(ws + OFFS), (int*)(ws + CURS),
        (int*)(ws + GTOT), (int)Nn);

    scatter_edges<<<idiv_up(Ee, 256), 256, 0, stream>>>(
        pos, ei, (int*)(ws + CURS), (int2*)(ws + CSR), (int)Ee);

    node_attn<<<idiv_up(Nn, 4), 256, 0, stream>>>(
        ws + QTAB, (const unsigned*)(ws + KVT),
        (const int2*)(ws + CSR), (const int*)(ws + OFFS),
        (const int*)(ws + DEG), batch,
        R1, b1, R2, b2, ws + POOL, (int)Nn);

    final_proj<<<idiv_up(out_size, 256), 256, 0, stream>>>(
        ws + POOL, Wproj, out, out_size);
}